// Round 11
// baseline (351.099 us; speedup 1.0000x reference)
//
#include <hip/hip_runtime.h>
#include <cstdint>
#include <cstddef>

// SimOTA-style dynamic-k matcher, B=16, Q=8400, C=80, G=64.
// Outputs INT32 concat: selected[B*Q], gt_assign[B*Q], matched_query_id[B*G].
// Pipeline: gather_cls -> build_cost -> column_select -> match.
//
// Exactness invariants (absmax=0 rounds 5-8, preserved):
//  - cls/iou/cost expressions bit-identical to reference order, just relocated.
//  - initial matching = dyn_k lex-(value,q)-smallest per column == sorted pool prefix.
//  - kcnt[q] replay of +100000.0f adds is bit-exact vs XLA's accumulated c2.
//  - pool = EXACT lex top-64 per column -> first kcnt==0 entry is true argmin;
//    all-64-penalized -> full-column fallback scan.
//  - stale one-hot rewrite = argmin of PENALIZED cost (tie collapse at ulp(1e5)).
//  - sticky fix flag == reference's any(popc>1).
//  - dyn_k = clamp(trunc(top-10 iou sum, descending order), 1, 10); top-10 multiset
//    exact (dup-preserving insertion + >= merge; union of per-thread top-10s
//    provably contains the global top-10 multiset).
//  - wave_hist_add: exited lanes leave EXEC -> excluded from __ballot; final
//    partial iteration has act=false for all lanes -> body skipped (no deadlock).

static constexpr int Bn = 16;
static constexpr int Qn = 8400;
static constexpr int Cn = 80;
static constexpr int Gn = 64;
#define TPB 512
#define MLIST_CAP 1536
#define STALE_CAP 320

__device__ __forceinline__ unsigned int ordf(float f) {
    unsigned int u = __float_as_uint(f);
    return u ^ ((unsigned int)((int)u >> 31) | 0x80000000u);
}
__device__ __forceinline__ float inv_ordf(unsigned int o) {
    unsigned int u = (o & 0x80000000u) ? (o ^ 0x80000000u) : ~o;
    return __uint_as_float(u);
}
__device__ __forceinline__ float replay_penalty(float v, unsigned int k) {
    for (unsigned int t = 0; t < k; ++t) v += 100000.0f;
    return v;
}
// one atomic per distinct bin per wave (vs 64-way serialized same-bin atomics)
__device__ __forceinline__ void wave_hist_add(unsigned int* hist, unsigned int bin, bool active) {
    const int lane = threadIdx.x & 63;
    unsigned long long act = __ballot(active);
    while (act) {
        int leader = __ffsll((unsigned long long)act) - 1;
        unsigned int lb = (unsigned int)__shfl((int)bin, leader, 64);
        unsigned long long same = __ballot(active && (bin == lb));
        if (lane == leader) atomicAdd(&hist[lb], (unsigned int)__popcll(same));
        act &= ~same;
    }
}

// ---------------- kernel 0: gather logits by label + focal cls term ----------------
__global__ __launch_bounds__(256)
void gather_cls_kernel(const float* __restrict__ logits,
                       const int*   __restrict__ labels,
                       float* __restrict__ cls_cm)
{
    const int b = blockIdx.y;
    const int q0 = blockIdx.x * 64;
    const int tid = threadIdx.x;
    const int qmax = (Qn - q0 < 64) ? (Qn - q0) : 64;

    __shared__ float sl[64][81];
    __shared__ int glab[Gn];
    if (tid < Gn) glab[tid] = labels[b*Gn + tid];
    for (int i = tid; i < 64*20; i += 256) {
        int row = i / 20, c4 = i % 20;
        if (row < qmax) {
            const float4 v = *(const float4*)&logits[((size_t)b*Qn + q0 + row)*Cn + c4*4];
            float* d = &sl[row][c4*4];
            d[0]=v.x; d[1]=v.y; d[2]=v.z; d[3]=v.w;
        }
    }
    __syncthreads();
    for (int j = tid; j < Gn*64; j += 256) {
        int g = j >> 6, qq = j & 63;
        if (qq < qmax) {
            float xlg = sl[qq][glab[g]];
            float p = 1.0f/(1.0f+expf(-xlg));
            float neg = 0.75f*(p*p)*(-logf(1.0f-p+1e-8f));
            float pos = 0.25f*((1.0f-p)*(1.0f-p))*(-logf(p+1e-8f));
            cls_cm[((size_t)b*Gn + g)*Qn + q0 + qq] = pos - neg;
        }
    }
}

// ---------------- kernel 1: cost matrix (geometry + streamed cls) ----------------
__global__ __launch_bounds__(256)
void build_cost_kernel(const float* __restrict__ pboxes,
                       const float* __restrict__ gboxes,
                       const float* __restrict__ cls_cm,
                       float* __restrict__ cost_cm,
                       unsigned char* __restrict__ rowarg)
{
    const int b = blockIdx.y;
    const int q = blockIdx.x * 256 + threadIdx.x;

    __shared__ float gx0[Gn], gy0[Gn], gx1[Gn], gy1[Gn];
    __shared__ float gcx[Gn], gcy[Gn], gar[Gn];
    if (threadIdx.x < Gn) {
        int g = threadIdx.x;
        const float* gb = &gboxes[((size_t)b*Gn + g)*4];
        float cx = gb[0], cy = gb[1], w = gb[2], h = gb[3];
        float x0 = cx - 0.5f*w, y0 = cy - 0.5f*h;
        float x1 = cx + 0.5f*w, y1 = cy + 0.5f*h;
        gx0[g]=x0; gy0[g]=y0; gx1[g]=x1; gy1[g]=y1;
        gcx[g]=cx; gcy[g]=cy;
        gar[g]=(x1-x0)*(y1-y0);
    }
    __syncthreads();
    if (q >= Qn) return;

    const float4 pb = *(const float4*)&pboxes[((size_t)b*Qn + q)*4];
    float cx = pb.x, cy = pb.y, w = pb.z, h = pb.w;
    float ax0 = cx - 0.5f*w, ay0 = cy - 0.5f*h;
    float ax1 = cx + 0.5f*w, ay1 = cy + 0.5f*h;
    float areaA = (ax1-ax0)*(ay1-ay0);
    const float r = 2.5f/32.0f;

    unsigned long long ibc = 0ull;
    bool anyBox=false, anyCtr=false;
    for (int g=0; g<Gn; ++g) {
        bool ib = (cx>gx0[g]) && (cx<gx1[g]) && (cy>gy0[g]) && (cy<gy1[g]);
        bool ic = (cx>gcx[g]-r) && (cx<gcx[g]+r) && (cy>gcy[g]-r) && (cy<gcy[g]+r);
        anyBox |= ib; anyCtr |= ic;
        if (ib && ic) ibc |= (1ull<<g);
    }
    float fgterm = (anyBox || anyCtr) ? 0.0f : 10000.0f;

    float rmin = __builtin_inff(); int rarg = 0;
    size_t obase = ((size_t)b*Gn)*Qn + q;
    for (int g=0; g<Gn; ++g) {
        float X0=gx0[g], Y0=gy0[g], X1=gx1[g], Y1=gy1[g];
        float ltx=fmaxf(ax0,X0), lty=fmaxf(ay0,Y0);
        float rbx=fminf(ax1,X1), rby=fminf(ay1,Y1);
        float wx=fmaxf(rbx-ltx,0.f), wy=fmaxf(rby-lty,0.f);
        float inter=wx*wy;
        float uni=(areaA+gar[g])-inter;
        float iou=inter/uni;
        float l2x=fminf(ax0,X0), l2y=fminf(ay0,Y0);
        float r2x=fmaxf(ax1,X1), r2y=fmaxf(ay1,Y1);
        float ex=fmaxf(r2x-l2x,0.f), ey=fmaxf(r2y-l2y,0.f);
        float enc=ex*ey;
        float giou = iou - (enc-uni)/enc;
        float cls = cls_cm[obase + (size_t)g*Qn];
        float iibc = ((ibc>>g)&1ull) ? 1.0f : 0.0f;
        float cost = ((cls + 3.0f*(-giou)) + 100.0f*(1.0f-iibc)) + fgterm;
        cost_cm[obase + (size_t)g*Qn] = cost;
        if (cost < rmin) { rmin = cost; rarg = g; }
    }
    rowarg[(size_t)b*Qn + q] = (unsigned char)rarg;
}

// ---------------- kernel 2: per-column dyn_k + exact sorted top-64 ----------------
__device__ __forceinline__ void hist_find(unsigned int* hist, unsigned int* chunk,
                                          unsigned int* s_bin, unsigned int* s_cb,
                                          unsigned int want, int tid)
{
    if (tid < 64) {
        unsigned int s = 0;
        for (int i = 0; i < 64; ++i) s += hist[tid*64 + i];
        chunk[tid] = s;
    }
    __syncthreads();
    if (tid == 0) {
        unsigned int acc = 0; int c = 0;
        for (; c < 63; ++c) { if (acc + chunk[c] >= want) break; acc += chunk[c]; }
        int bbase = c*64; unsigned int bb = 0;
        for (; bb < 63; ++bb) { unsigned int h = hist[bbase+bb]; if (acc + h >= want) break; acc += h; }
        *s_bin = (unsigned int)(bbase + bb);
        *s_cb  = acc;
    }
    __syncthreads();
}

// merge 8 sorted-descending 10-lists (stride-11 LDS) into m[10] (registers)
__device__ __forceinline__ void merge8_desc(const float* tl, int first, float* m) {
    int ptr[8] = {0,0,0,0,0,0,0,0};
    #pragma unroll
    for (int t=0;t<10;++t) {
        float best = -2.0f; int bu = 0;
        #pragma unroll
        for (int u=0;u<8;++u) {
            float v = (ptr[u] < 10) ? tl[(first+u)*11 + ptr[u]] : -2.0f;
            if (v > best) { best = v; bu = u; }
        }
        ptr[bu]++;
        m[t] = best;
    }
}

__global__ __launch_bounds__(512)
void column_select_kernel(const float* __restrict__ cost_all,
                          const float* __restrict__ pboxes,
                          const float* __restrict__ gboxes,
                          int*   __restrict__ dynk_all,
                          float* __restrict__ poolv_all,
                          int*   __restrict__ poolq_all)
{
    const int g = blockIdx.x, b = blockIdx.y, tid = threadIdx.x;
    const float* ccol = cost_all + ((size_t)b*Gn + g)*Qn;

    // phase union: phase1 tl[512][11] f32 = 22528 B; phase2 ord[8400]+hist[4096] = 50048 B
    __shared__ __align__(16) char u_smem[50048];
    __shared__ unsigned int chunk[64];
    __shared__ unsigned int s_bin1, s_bin2, s_bin3, s_cb1, s_cb2, s_cb3;
    __shared__ unsigned int s_nb, s_nt;
    __shared__ float pv[64]; __shared__ int pq[64];
    __shared__ float sv[64]; __shared__ int sq[64];
    __shared__ int tq[64];

    // ---- phase 1: dyn_k from on-the-fly iou; 3-level 8-way merges ----
    {
        const float* gb = &gboxes[((size_t)b*Gn + g)*4];
        float gcx_=gb[0], gcy_=gb[1], gw=gb[2], gh=gb[3];
        float X0=gcx_-0.5f*gw, Y0=gcy_-0.5f*gh, X1=gcx_+0.5f*gw, Y1=gcy_+0.5f*gh;
        float garea=(X1-X0)*(Y1-Y0);
        const float4* pb4 = (const float4*)(pboxes + (size_t)b*Qn*4);

        float* tl = (float*)u_smem;          // [512][11]
        float tv[10];
        #pragma unroll
        for (int i=0;i<10;i++) tv[i] = -1.0f;
        for (int j=tid; j<Qn; j+=512) {
            float4 pb = pb4[j];
            float ax0=pb.x-0.5f*pb.z, ay0=pb.y-0.5f*pb.w;
            float ax1=pb.x+0.5f*pb.z, ay1=pb.y+0.5f*pb.w;
            float areaA=(ax1-ax0)*(ay1-ay0);
            float ltx=fmaxf(ax0,X0), lty=fmaxf(ay0,Y0);
            float rbx=fminf(ax1,X1), rby=fminf(ay1,Y1);
            float wx=fmaxf(rbx-ltx,0.f), wy=fmaxf(rby-lty,0.f);
            float inter=wx*wy;
            float uni=(areaA+garea)-inter;
            float v=inter/uni;
            if (v > tv[9]) {
                int k = 9;
                #pragma unroll
                for (int s=9; s>0; --s) { if (v > tv[s-1]) { tv[s]=tv[s-1]; k=s-1; } }
                tv[k]=v;
            }
        }
        #pragma unroll
        for (int i=0;i<10;i++) tl[tid*11+i]=tv[i];
        __syncthreads();
        float m[10];
        if (tid < 64) { merge8_desc(tl, tid*8, m); }
        __syncthreads();
        if (tid < 64) {
            #pragma unroll
            for (int i=0;i<10;i++) tl[tid*11+i]=m[i];
        }
        __syncthreads();
        if (tid < 8)  { merge8_desc(tl, tid*8, m); }
        __syncthreads();
        if (tid < 8)  {
            #pragma unroll
            for (int i=0;i<10;i++) tl[tid*11+i]=m[i];
        }
        __syncthreads();
        if (tid == 0) {
            merge8_desc(tl, 0, m);
            float s = 0.0f;
            #pragma unroll
            for (int i=0;i<10;i++) s += m[i];
            int k = (int)s;
            if (k < 1) k = 1;
            if (k > 10) k = 10;
            dynk_all[b*Gn + g] = k;
        }
    }
    __syncthreads();

    // ---- phase 2: exact lex-(cost,q) top-64 via 3-level radix, ord cached,
    //               wave-aggregated histogram atomics ----
    {
        unsigned int* s_ord = (unsigned int*)u_smem;              // [8400]
        unsigned int* hist  = (unsigned int*)(u_smem + 33664);    // [4096]
        const unsigned int want = 64;

        for (int i=tid;i<4096;i+=512) hist[i]=0u;
        __syncthreads();
        for (int j=tid; j<Qn+511; j+=512) {
            bool act = (j < Qn);
            unsigned int od = 0u;
            if (act) { od = ordf(ccol[j]); s_ord[j] = od; }
            wave_hist_add(hist, od>>20, act);
        }
        __syncthreads();
        hist_find(hist, chunk, &s_bin1, &s_cb1, want, tid);

        for (int i=tid;i<4096;i+=512) hist[i]=0u;
        __syncthreads();
        for (int j=tid; j<Qn+511; j+=512) {
            bool act = (j < Qn);
            unsigned int od = act ? s_ord[j] : 0u;
            wave_hist_add(hist, (od>>8)&0xFFFu, act && ((od>>20)==s_bin1));
        }
        __syncthreads();
        hist_find(hist, chunk, &s_bin2, &s_cb2, want - s_cb1, tid);

        for (int i=tid;i<4096;i+=512) hist[i]=0u;
        __syncthreads();
        unsigned int hi24 = (s_bin1<<12) | s_bin2;
        for (int j=tid; j<Qn+511; j+=512) {
            bool act = (j < Qn);
            unsigned int od = act ? s_ord[j] : 0u;
            wave_hist_add(hist, od&0xFFu, act && ((od>>8)==hi24));
        }
        __syncthreads();
        hist_find(hist, chunk, &s_bin3, &s_cb3, want - s_cb1 - s_cb2, tid);

        const unsigned int thr = (s_bin1<<20) | (s_bin2<<8) | s_bin3;
        const unsigned int c_strict = s_cb1 + s_cb2 + s_cb3;
        const unsigned int t_take = want - c_strict;
        if (tid==0) { s_nb=0u; s_nt=0u; }
        __syncthreads();
        for (int j=tid;j<Qn;j+=512) {
            unsigned int od = s_ord[j];
            if (od < thr) {
                unsigned int pos = atomicAdd(&s_nb,1u);
                if (pos < 64u) { pv[pos]=inv_ordf(od); pq[pos]=j; }
            } else if (od == thr) {
                unsigned int pos = atomicAdd(&s_nt,1u);
                if (pos < 64u) tq[pos]=j;
            }
        }
        __syncthreads();
        if (tid==0) {
            float thrv = inv_ordf(thr);
            int nt = (int)s_nt; if (nt > 64) nt = 64;
            for (int i=1;i<nt;++i){ int x=tq[i]; int k=i; while(k>0 && tq[k-1]>x){tq[k]=tq[k-1];--k;} tq[k]=x; }
            for (unsigned int r=0; r<t_take && (int)r<nt; ++r) { pv[c_strict+r]=thrv; pq[c_strict+r]=tq[r]; }
        }
        __syncthreads();
        if (tid < 64) {
            float v = pv[tid]; int qq = pq[tid];
            int rank = 0;
            for (int j=0;j<64;++j) {
                float u = pv[j]; int uq = pq[j];
                if (u < v || (u==v && uq<qq)) ++rank;
            }
            sv[rank]=v; sq[rank]=qq;
        }
        __syncthreads();
        if (tid < 64) {
            size_t base = ((size_t)b*Gn + g)*64 + tid;
            poolv_all[base] = sv[tid];
            poolq_all[base] = sq[tid];
        }
    }
}

// ---------------- kernel 3: serial matching loop (pool-driven) ----------------
__global__ __launch_bounds__(TPB)
void match_kernel(const float* __restrict__ cost_all,
                  const unsigned char* __restrict__ rowarg_all,
                  const int*   __restrict__ dynk_all,
                  const float* __restrict__ poolv_all,
                  const int*   __restrict__ poolq_all,
                  unsigned long long* __restrict__ mmask_all,
                  int* __restrict__ out)
{
    const int b = blockIdx.x;
    const int tid = threadIdx.x;
    const float* costb = cost_all + (size_t)b*Gn*Qn;
    const unsigned char* rarg = rowarg_all + (size_t)b*Qn;
    unsigned long long* mmask = mmask_all + (size_t)b*Qn;

    __shared__ __align__(16) unsigned long long s_pool_raw[2048];
    __shared__ int s_pq[Gn*64];
    __shared__ unsigned short s_kcnt[Qn];
    __shared__ int s_mlist[MLIST_CAP];
    __shared__ int s_staleq[STALE_CAP], s_stalec[STALE_CAP];
    __shared__ float s_mv[TPB]; __shared__ int s_mi[TPB];
    __shared__ int s_dynk[Gn];
    __shared__ unsigned int s_colcnt[Gn];
    __shared__ int s_winq[Gn];
    __shared__ unsigned long long s_unm, s_fbmask;
    __shared__ int s_mn, s_scnt, s_fix;

    float* s_pv = (float*)s_pool_raw;

    for (int q=tid; q<Qn; q+=TPB) s_kcnt[q]=0;
    for (int i=tid; i<Gn*64; i+=TPB) {
        size_t base = (size_t)b*Gn*64 + i;
        s_pv[i] = poolv_all[base];
        s_pq[i] = poolq_all[base];
    }
    if (tid < Gn) { s_dynk[tid] = dynk_all[b*Gn+tid]; s_colcnt[tid]=0u; }
    for (int q=tid; q<Qn; q+=TPB) mmask[q]=0ull;
    if (tid==0) { s_mn=0; s_scnt=0; s_fix=0; }
    __syncthreads();

    // PB: initial matching = first dyn_k entries of each sorted pool
    if (tid < Gn) {
        int k = s_dynk[tid];
        unsigned long long bit = 1ull<<tid;
        for (int t=0; t<k; ++t) {
            int q = s_pq[tid*64 + t];
            unsigned long long old = atomicOr(&mmask[q], bit);
            if (old == 0ull) {
                int pos = atomicAdd(&s_mn,1);
                if (pos < MLIST_CAP) s_mlist[pos]=q;
            }
        }
    }
    __syncthreads();
    int mn = s_mn; if (mn > MLIST_CAP) mn = MLIST_CAP;

    // PC: stale rows -> one-hot at rowarg
    for (int j=tid; j<mn; j+=TPB) {
        int q = s_mlist[j];
        unsigned long long m = atomicOr(&mmask[q], 0ull);
        if (__popcll(m) > 1) {
            int pos = atomicAdd(&s_scnt,1);
            int rp = rarg[q];
            if (pos < STALE_CAP) { s_staleq[pos]=q; s_stalec[pos]=rp; }
            atomicExch(&mmask[q], 1ull<<rp);
        }
    }
    __syncthreads();
    const int scnt = (s_scnt < STALE_CAP) ? s_scnt : STALE_CAP;
    for (int j=tid; j<mn; j+=TPB) {
        unsigned long long m = atomicOr(&mmask[s_mlist[j]], 0ull);
        while (m) { int gg = __ffsll(m)-1; m &= m-1ull; atomicAdd(&s_colcnt[gg],1u); }
    }
    __syncthreads();

    // PD: while any column unmatched
    for (int iter=0; iter<1024; ++iter) {
        if (tid < 64) {
            unsigned long long bal = __ballot(s_colcnt[tid]==0u);
            if (tid==0) { s_unm = bal; s_fbmask = 0ull; }
        }
        __syncthreads();
        const unsigned long long unm = s_unm;
        if (unm == 0ull) break;
        mn = s_mn; if (mn > MLIST_CAP) mn = MLIST_CAP;

        for (int j=tid; j<mn; j+=TPB) s_kcnt[s_mlist[j]]++;
        __syncthreads();

        int wq = -1;
        if (tid < 64 && ((unm>>tid)&1ull)) {
            for (int t=0; t<64; ++t) {
                int q = s_pq[tid*64 + t];
                if (s_kcnt[q]==0) { wq=q; break; }
            }
            if (wq < 0) atomicOr(&s_fbmask, 1ull<<tid);
        }
        __syncthreads();
        unsigned long long fb = s_fbmask;
        while (fb) {
            int c = __ffsll(fb)-1; fb &= fb-1ull;
            float bv=__builtin_inff(); int bq=0x7fffffff;
            for (int j=tid; j<Qn; j+=TPB) {
                if (s_kcnt[j]==0) {
                    float v = costb[(size_t)c*Qn + j];
                    if (v<bv || (v==bv && j<bq)) { bv=v; bq=j; }
                }
            }
            s_mv[tid]=bv; s_mi[tid]=bq;
            __syncthreads();
            for (int s=TPB/2; s>0; s>>=1) {
                if (tid<s) {
                    float v2=s_mv[tid+s]; int q2=s_mi[tid+s];
                    if (v2<s_mv[tid] || (v2==s_mv[tid] && q2<s_mi[tid])) { s_mv[tid]=v2; s_mi[tid]=q2; }
                }
                __syncthreads();
            }
            if (tid==0) s_winq[c]=s_mi[0];
            __syncthreads();
        }
        if (tid<64 && wq<0 && ((unm>>tid)&1ull)) wq = s_winq[tid];

        if (tid<64 && ((unm>>tid)&1ull) && wq>=0 && wq<Qn) {
            unsigned long long bit = 1ull<<tid;
            unsigned long long old = atomicOr(&mmask[wq], bit);
            if (old==0ull) {
                int pos = atomicAdd(&s_mn,1);
                if (pos < MLIST_CAP) s_mlist[pos]=wq;
            }
            if (__popcll(old|bit) > 1) s_fix = 1;
            atomicAdd(&s_colcnt[tid],1u);
        }
        __syncthreads();

        if (s_fix) {
            for (int j=tid; j<scnt; j+=TPB) {
                int q = s_staleq[j];
                unsigned int kk = s_kcnt[q];
                float best=__builtin_inff(); int bg=0;
                for (int gg=0; gg<Gn; ++gg) {
                    float v = replay_penalty(costb[(size_t)gg*Qn + q], kk);
                    if (v < best) { best=v; bg=gg; }
                }
                int oc = s_stalec[j];
                if (bg != oc) {
                    atomicAdd(&s_colcnt[oc], (unsigned int)-1);
                    atomicAdd(&s_colcnt[bg], 1u);
                    s_stalec[j] = bg;
                    atomicExch(&mmask[q], 1ull<<bg);
                }
            }
        }
        __syncthreads();
    }

    // PE: outputs (int32)
    __syncthreads();
    mn = s_mn; if (mn > MLIST_CAP) mn = MLIST_CAP;
    unsigned long long* s_mcache = s_pool_raw;
    for (int j=tid; j<mn; j+=TPB) s_mcache[j] = atomicOr(&mmask[s_mlist[j]], 0ull);
    for (int q=tid; q<Qn; q+=TPB) {
        out[(size_t)b*Qn + q] = 0;
        out[(size_t)Bn*Qn + (size_t)b*Qn + q] = 0;
    }
    __syncthreads();
    for (int j=tid; j<mn; j+=TPB) {
        int q = s_mlist[j];
        unsigned long long m = s_mcache[j];
        out[(size_t)b*Qn + q] = 1;
        out[(size_t)Bn*Qn + (size_t)b*Qn + q] = __ffsll(m)-1;
    }
    __syncthreads();
    {
        const int g = tid>>3, p = tid&7;
        float best=__builtin_inff(); int bq=0x7fffffff;
        for (int j=p; j<mn; j+=8) {
            unsigned long long m = s_mcache[j];
            if ((m>>g)&1ull) {
                int q = s_mlist[j];
                float v = replay_penalty(costb[(size_t)g*Qn+q], s_kcnt[q]);
                if (v<best || (v==best && q<bq)) { best=v; bq=q; }
            }
        }
        s_mv[tid]=best; s_mi[tid]=bq;
    }
    __syncthreads();
    if (tid < Gn) {
        float best=__builtin_inff(); int bq=0x7fffffff;
        #pragma unroll
        for (int u=0;u<8;++u) {
            float v=s_mv[tid*8+u]; int qq=s_mi[tid*8+u];
            if (v<best || (v==best && qq<bq)) { best=v; bq=qq; }
        }
        if (bq>=Qn) bq=0;
        out[(size_t)2*Bn*Qn + (size_t)b*Gn + tid] = bq;
    }
}

extern "C" void kernel_launch(void* const* d_in, const int* in_sizes, int n_in,
                              void* d_out, int out_size, void* d_ws, size_t ws_size,
                              hipStream_t stream)
{
    const float* logits = (const float*)d_in[0];
    const float* pboxes = (const float*)d_in[1];
    const int*   labels = (const int*)d_in[2];
    const float* gboxes = (const float*)d_in[3];
    int* out = (int*)d_out;

    char* ws = (char*)d_ws;
    size_t off = 0;
    float* cost_cm = (float*)(ws + off); off += (size_t)Bn*Gn*Qn*sizeof(float);
    float* cls_cm  = (float*)(ws + off); off += (size_t)Bn*Gn*Qn*sizeof(float);
    unsigned long long* mmask = (unsigned long long*)(ws + off); off += (size_t)Bn*Qn*sizeof(unsigned long long);
    float* poolv = (float*)(ws + off); off += (size_t)Bn*Gn*64*sizeof(float);
    int*   poolq = (int*)(ws + off);   off += (size_t)Bn*Gn*64*sizeof(int);
    int*   dynk  = (int*)(ws + off);   off += (size_t)Bn*Gn*sizeof(int);
    unsigned char* rowarg = (unsigned char*)(ws + off); off += (size_t)Bn*Qn;

    dim3 g0((Qn + 63)/64, Bn);
    gather_cls_kernel<<<g0, 256, 0, stream>>>(logits, labels, cls_cm);
    dim3 g1((Qn + 255)/256, Bn);
    build_cost_kernel<<<g1, 256, 0, stream>>>(pboxes, gboxes, cls_cm,
                                              cost_cm, rowarg);
    dim3 g2(Gn, Bn);
    column_select_kernel<<<g2, 512, 0, stream>>>(cost_cm, pboxes, gboxes,
                                                 dynk, poolv, poolq);
    match_kernel<<<Bn, TPB, 0, stream>>>(cost_cm, rowarg, dynk, poolv, poolq, mmask, out);
}

// Round 12
// 274.448 us; speedup vs baseline: 1.2793x; 1.2793x over previous
//
#include <hip/hip_runtime.h>
#include <cstdint>
#include <cstddef>

// SimOTA-style dynamic-k matcher, B=16, Q=8400, C=80, G=64.
// Outputs INT32 concat: selected[B*Q], gt_assign[B*Q], matched_query_id[B*G].
// Pipeline: gather_cls -> build_cost -> column_select -> match.
//
// Exactness invariants (absmax=0 rounds 5-8,11, preserved):
//  - cls/iou/cost expressions bit-identical to reference order, just relocated.
//  - pool = EXACT sorted lex-(cost,q) top-64 per column. Costs are tri-modal:
//    iibc cluster [-20,25] < 50 < fg cluster [80,125] < bg [~10100]. If
//    n1=#{cost<50} >= 64 the top-64 all lie in cluster 1 -> exact rank-sort of
//    compacted candidates (u64 key = ordf(cost)<<32|q; integer order==lex order).
//    Else (rare, ~1.4% of columns) exact 64-step min-extraction over the column.
//  - kcnt[q] replay of +100000.0f adds is bit-exact vs XLA's accumulated c2.
//  - stale one-hot rewrite = argmin of PENALIZED cost; sticky fix flag.
//  - dyn_k = clamp(trunc(top-10 iou sum, desc order), 1, 10); multiset-exact.

static constexpr int Bn = 16;
static constexpr int Qn = 8400;
static constexpr int Cn = 80;
static constexpr int Gn = 64;
#define TPB 512
#define MLIST_CAP 1536
#define STALE_CAP 320
#define CAND_CAP 4096

__device__ __forceinline__ unsigned int ordf(float f) {
    unsigned int u = __float_as_uint(f);
    return u ^ ((unsigned int)((int)u >> 31) | 0x80000000u);
}
__device__ __forceinline__ float inv_ordf(unsigned int o) {
    unsigned int u = (o & 0x80000000u) ? (o ^ 0x80000000u) : ~o;
    return __uint_as_float(u);
}
__device__ __forceinline__ float replay_penalty(float v, unsigned int k) {
    for (unsigned int t = 0; t < k; ++t) v += 100000.0f;
    return v;
}

// ---------------- kernel 0: gather logits by label + focal cls term ----------------
__global__ __launch_bounds__(256)
void gather_cls_kernel(const float* __restrict__ logits,
                       const int*   __restrict__ labels,
                       float* __restrict__ cls_cm)
{
    const int b = blockIdx.y;
    const int q0 = blockIdx.x * 64;
    const int tid = threadIdx.x;
    const int qmax = (Qn - q0 < 64) ? (Qn - q0) : 64;

    __shared__ float sl[64][81];
    __shared__ int glab[Gn];
    if (tid < Gn) glab[tid] = labels[b*Gn + tid];
    for (int i = tid; i < 64*20; i += 256) {
        int row = i / 20, c4 = i % 20;
        if (row < qmax) {
            const float4 v = *(const float4*)&logits[((size_t)b*Qn + q0 + row)*Cn + c4*4];
            float* d = &sl[row][c4*4];
            d[0]=v.x; d[1]=v.y; d[2]=v.z; d[3]=v.w;
        }
    }
    __syncthreads();
    for (int j = tid; j < Gn*64; j += 256) {
        int g = j >> 6, qq = j & 63;
        if (qq < qmax) {
            float xlg = sl[qq][glab[g]];
            float p = 1.0f/(1.0f+expf(-xlg));
            float neg = 0.75f*(p*p)*(-logf(1.0f-p+1e-8f));
            float pos = 0.25f*((1.0f-p)*(1.0f-p))*(-logf(p+1e-8f));
            cls_cm[((size_t)b*Gn + g)*Qn + q0 + qq] = pos - neg;
        }
    }
}

// ---------------- kernel 1: cost matrix (geometry + streamed cls) ----------------
__global__ __launch_bounds__(256)
void build_cost_kernel(const float* __restrict__ pboxes,
                       const float* __restrict__ gboxes,
                       const float* __restrict__ cls_cm,
                       float* __restrict__ cost_cm,
                       unsigned char* __restrict__ rowarg)
{
    const int b = blockIdx.y;
    const int q = blockIdx.x * 256 + threadIdx.x;

    __shared__ float gx0[Gn], gy0[Gn], gx1[Gn], gy1[Gn];
    __shared__ float gcx[Gn], gcy[Gn], gar[Gn];
    if (threadIdx.x < Gn) {
        int g = threadIdx.x;
        const float* gb = &gboxes[((size_t)b*Gn + g)*4];
        float cx = gb[0], cy = gb[1], w = gb[2], h = gb[3];
        float x0 = cx - 0.5f*w, y0 = cy - 0.5f*h;
        float x1 = cx + 0.5f*w, y1 = cy + 0.5f*h;
        gx0[g]=x0; gy0[g]=y0; gx1[g]=x1; gy1[g]=y1;
        gcx[g]=cx; gcy[g]=cy;
        gar[g]=(x1-x0)*(y1-y0);
    }
    __syncthreads();
    if (q >= Qn) return;

    const float4 pb = *(const float4*)&pboxes[((size_t)b*Qn + q)*4];
    float cx = pb.x, cy = pb.y, w = pb.z, h = pb.w;
    float ax0 = cx - 0.5f*w, ay0 = cy - 0.5f*h;
    float ax1 = cx + 0.5f*w, ay1 = cy + 0.5f*h;
    float areaA = (ax1-ax0)*(ay1-ay0);
    const float r = 2.5f/32.0f;

    unsigned long long ibc = 0ull;
    bool anyBox=false, anyCtr=false;
    for (int g=0; g<Gn; ++g) {
        bool ib = (cx>gx0[g]) && (cx<gx1[g]) && (cy>gy0[g]) && (cy<gy1[g]);
        bool ic = (cx>gcx[g]-r) && (cx<gcx[g]+r) && (cy>gcy[g]-r) && (cy<gcy[g]+r);
        anyBox |= ib; anyCtr |= ic;
        if (ib && ic) ibc |= (1ull<<g);
    }
    float fgterm = (anyBox || anyCtr) ? 0.0f : 10000.0f;

    float rmin = __builtin_inff(); int rarg = 0;
    size_t obase = ((size_t)b*Gn)*Qn + q;
    for (int g=0; g<Gn; ++g) {
        float X0=gx0[g], Y0=gy0[g], X1=gx1[g], Y1=gy1[g];
        float ltx=fmaxf(ax0,X0), lty=fmaxf(ay0,Y0);
        float rbx=fminf(ax1,X1), rby=fminf(ay1,Y1);
        float wx=fmaxf(rbx-ltx,0.f), wy=fmaxf(rby-lty,0.f);
        float inter=wx*wy;
        float uni=(areaA+gar[g])-inter;
        float iou=inter/uni;
        float l2x=fminf(ax0,X0), l2y=fminf(ay0,Y0);
        float r2x=fmaxf(ax1,X1), r2y=fmaxf(ay1,Y1);
        float ex=fmaxf(r2x-l2x,0.f), ey=fmaxf(r2y-l2y,0.f);
        float enc=ex*ey;
        float giou = iou - (enc-uni)/enc;
        float cls = cls_cm[obase + (size_t)g*Qn];
        float iibc = ((ibc>>g)&1ull) ? 1.0f : 0.0f;
        float cost = ((cls + 3.0f*(-giou)) + 100.0f*(1.0f-iibc)) + fgterm;
        cost_cm[obase + (size_t)g*Qn] = cost;
        if (cost < rmin) { rmin = cost; rarg = g; }
    }
    rowarg[(size_t)b*Qn + q] = (unsigned char)rarg;
}

// ---------------- kernel 2: per-column dyn_k + exact sorted top-64 ----------------
// merge 8 sorted-descending 10-lists (stride-11 LDS) into m[10] (registers)
__device__ __forceinline__ void merge8_desc(const float* tl, int first, float* m) {
    int ptr[8] = {0,0,0,0,0,0,0,0};
    #pragma unroll
    for (int t=0;t<10;++t) {
        float best = -2.0f; int bu = 0;
        #pragma unroll
        for (int u=0;u<8;++u) {
            float v = (ptr[u] < 10) ? tl[(first+u)*11 + ptr[u]] : -2.0f;
            if (v > best) { best = v; bu = u; }
        }
        ptr[bu]++;
        m[t] = best;
    }
}

__global__ __launch_bounds__(512)
void column_select_kernel(const float* __restrict__ cost_all,
                          const float* __restrict__ pboxes,
                          const float* __restrict__ gboxes,
                          int*   __restrict__ dynk_all,
                          float* __restrict__ poolv_all,
                          int*   __restrict__ poolq_all)
{
    const int g = blockIdx.x, b = blockIdx.y, tid = threadIdx.x;
    const int lane = tid & 63, wid = tid >> 6;
    const float* ccol = cost_all + ((size_t)b*Gn + g)*Qn;

    // phase union: phase1 tl[512*11] f32 = 22528B; phase2 cand[4096] u64 = 32768B
    __shared__ __align__(16) char u_smem[32768];
    __shared__ unsigned long long s_w[8];
    __shared__ unsigned long long s_last;
    __shared__ unsigned int s_n1, s_pos;
    __shared__ float sv[64]; __shared__ int sq[64];

    // ---- phase 1: dyn_k from on-the-fly iou; 3-level 8-way merges ----
    {
        const float* gb = &gboxes[((size_t)b*Gn + g)*4];
        float gcx_=gb[0], gcy_=gb[1], gw=gb[2], gh=gb[3];
        float X0=gcx_-0.5f*gw, Y0=gcy_-0.5f*gh, X1=gcx_+0.5f*gw, Y1=gcy_+0.5f*gh;
        float garea=(X1-X0)*(Y1-Y0);
        const float4* pb4 = (const float4*)(pboxes + (size_t)b*Qn*4);

        float* tl = (float*)u_smem;          // [512][11]
        float tv[10];
        #pragma unroll
        for (int i=0;i<10;i++) tv[i] = -1.0f;
        for (int j=tid; j<Qn; j+=512) {
            float4 pb = pb4[j];
            float ax0=pb.x-0.5f*pb.z, ay0=pb.y-0.5f*pb.w;
            float ax1=pb.x+0.5f*pb.z, ay1=pb.y+0.5f*pb.w;
            float areaA=(ax1-ax0)*(ay1-ay0);
            float ltx=fmaxf(ax0,X0), lty=fmaxf(ay0,Y0);
            float rbx=fminf(ax1,X1), rby=fminf(ay1,Y1);
            float wx=fmaxf(rbx-ltx,0.f), wy=fmaxf(rby-lty,0.f);
            float inter=wx*wy;
            float uni=(areaA+garea)-inter;
            float v=inter/uni;
            if (v > tv[9]) {
                int k = 9;
                #pragma unroll
                for (int s=9; s>0; --s) { if (v > tv[s-1]) { tv[s]=tv[s-1]; k=s-1; } }
                tv[k]=v;
            }
        }
        #pragma unroll
        for (int i=0;i<10;i++) tl[tid*11+i]=tv[i];
        __syncthreads();
        float m[10];
        if (tid < 64) { merge8_desc(tl, tid*8, m); }
        __syncthreads();
        if (tid < 64) {
            #pragma unroll
            for (int i=0;i<10;i++) tl[tid*11+i]=m[i];
        }
        __syncthreads();
        if (tid < 8)  { merge8_desc(tl, tid*8, m); }
        __syncthreads();
        if (tid < 8)  {
            #pragma unroll
            for (int i=0;i<10;i++) tl[tid*11+i]=m[i];
        }
        __syncthreads();
        if (tid == 0) {
            merge8_desc(tl, 0, m);
            float s = 0.0f;
            #pragma unroll
            for (int i=0;i<10;i++) s += m[i];
            int k = (int)s;
            if (k < 1) k = 1;
            if (k > 10) k = 10;
            dynk_all[b*Gn + g] = k;
        }
    }
    __syncthreads();   // tl dead

    // ---- phase 2: exact sorted lex-(cost,q) top-64 ----
    {
        const unsigned int thr50 = ordf(50.0f);
        unsigned int kord[17];                 // per-thread ord cache (17 VGPRs)
        int cnt = 0;
        #pragma unroll
        for (int t=0;t<17;++t) {
            int j = tid + t*512;
            if (j < Qn) {
                unsigned int od = ordf(ccol[j]);
                kord[t] = od;
                cnt += (od < thr50) ? 1 : 0;
            } else kord[t] = 0xFFFFFFFFu;
        }
        // block-reduce cnt -> s_n1
        #pragma unroll
        for (int off=32; off>0; off>>=1) cnt += __shfl_down(cnt, off, 64);
        if (tid==0) s_n1 = 0u;
        __syncthreads();
        if (lane==0) atomicAdd(&s_n1, (unsigned int)cnt);
        __syncthreads();
        const unsigned int n1 = s_n1;

        if (n1 >= 64u && n1 <= (unsigned)CAND_CAP) {
            // compact cluster-1 candidates, then rank-sort (exact, keys distinct)
            unsigned long long* cand = (unsigned long long*)u_smem;
            if (tid==0) s_pos = 0u;
            __syncthreads();
            #pragma unroll
            for (int t=0;t<17;++t) {
                bool pred = (kord[t] < thr50);
                unsigned long long mask = __ballot(pred);
                if (mask) {
                    int leader = __ffsll(mask)-1;
                    unsigned int base = 0u;
                    if (lane == leader) base = atomicAdd(&s_pos, (unsigned int)__popcll(mask));
                    base = (unsigned int)__shfl((int)base, leader, 64);
                    if (pred) {
                        unsigned int pre = (unsigned int)__popcll(mask & ((1ull<<lane)-1ull));
                        int j = tid + t*512;
                        cand[base + pre] = ((unsigned long long)kord[t]<<32) | (unsigned int)j;
                    }
                }
            }
            __syncthreads();
            for (unsigned int i=tid; i<n1; i+=512) {
                unsigned long long k = cand[i];
                int rank = 0;
                for (unsigned int j=0; j<n1; ++j) rank += (cand[j] < k) ? 1 : 0;
                if (rank < 64) {
                    sv[rank] = inv_ordf((unsigned int)(k>>32));
                    sq[rank] = (int)(k & 0xFFFFFFFFu);
                }
            }
        } else {
            // rare path: exact 64-step min-extraction (register scan + shuffle reduce)
            unsigned long long last = 0ull;
            for (int r=0; r<64; ++r) {
                unsigned long long lm = ~0ull;
                #pragma unroll
                for (int t=0;t<17;++t) {
                    int j = tid + t*512;
                    unsigned long long k = ((unsigned long long)kord[t]<<32) | (unsigned int)j;
                    if (k > last && k < lm) lm = k;
                }
                #pragma unroll
                for (int off=32; off>0; off>>=1) {
                    unsigned long long o = __shfl_down(lm, off, 64);
                    if (o < lm) lm = o;
                }
                if (lane==0) s_w[wid] = lm;
                __syncthreads();
                if (tid==0) {
                    unsigned long long m = s_w[0];
                    #pragma unroll
                    for (int u=1;u<8;++u) if (s_w[u] < m) m = s_w[u];
                    s_last = m;
                    sv[r] = inv_ordf((unsigned int)(m>>32));
                    sq[r] = (int)(m & 0xFFFFFFFFu);
                }
                __syncthreads();
                last = s_last;
            }
        }
        __syncthreads();
        if (tid < 64) {
            size_t base = ((size_t)b*Gn + g)*64 + tid;
            poolv_all[base] = sv[tid];
            poolq_all[base] = sq[tid];
        }
    }
}

// ---------------- kernel 3: serial matching loop (pool-driven) ----------------
__global__ __launch_bounds__(TPB)
void match_kernel(const float* __restrict__ cost_all,
                  const unsigned char* __restrict__ rowarg_all,
                  const int*   __restrict__ dynk_all,
                  const float* __restrict__ poolv_all,
                  const int*   __restrict__ poolq_all,
                  unsigned long long* __restrict__ mmask_all,
                  int* __restrict__ out)
{
    const int b = blockIdx.x;
    const int tid = threadIdx.x;
    const float* costb = cost_all + (size_t)b*Gn*Qn;
    const unsigned char* rarg = rowarg_all + (size_t)b*Qn;
    unsigned long long* mmask = mmask_all + (size_t)b*Qn;

    __shared__ __align__(16) unsigned long long s_pool_raw[2048];
    __shared__ int s_pq[Gn*64];
    __shared__ unsigned short s_kcnt[Qn];
    __shared__ int s_mlist[MLIST_CAP];
    __shared__ int s_staleq[STALE_CAP], s_stalec[STALE_CAP];
    __shared__ float s_mv[TPB]; __shared__ int s_mi[TPB];
    __shared__ int s_dynk[Gn];
    __shared__ unsigned int s_colcnt[Gn];
    __shared__ int s_winq[Gn];
    __shared__ unsigned long long s_unm, s_fbmask;
    __shared__ int s_mn, s_scnt, s_fix;

    float* s_pv = (float*)s_pool_raw;

    for (int q=tid; q<Qn; q+=TPB) s_kcnt[q]=0;
    for (int i=tid; i<Gn*64; i+=TPB) {
        size_t base = (size_t)b*Gn*64 + i;
        s_pv[i] = poolv_all[base];
        s_pq[i] = poolq_all[base];
    }
    if (tid < Gn) { s_dynk[tid] = dynk_all[b*Gn+tid]; s_colcnt[tid]=0u; }
    for (int q=tid; q<Qn; q+=TPB) mmask[q]=0ull;
    if (tid==0) { s_mn=0; s_scnt=0; s_fix=0; }
    __syncthreads();

    // PB: initial matching = first dyn_k entries of each sorted pool
    if (tid < Gn) {
        int k = s_dynk[tid];
        unsigned long long bit = 1ull<<tid;
        for (int t=0; t<k; ++t) {
            int q = s_pq[tid*64 + t];
            unsigned long long old = atomicOr(&mmask[q], bit);
            if (old == 0ull) {
                int pos = atomicAdd(&s_mn,1);
                if (pos < MLIST_CAP) s_mlist[pos]=q;
            }
        }
    }
    __syncthreads();
    int mn = s_mn; if (mn > MLIST_CAP) mn = MLIST_CAP;

    // PC: stale rows -> one-hot at rowarg
    for (int j=tid; j<mn; j+=TPB) {
        int q = s_mlist[j];
        unsigned long long m = atomicOr(&mmask[q], 0ull);
        if (__popcll(m) > 1) {
            int pos = atomicAdd(&s_scnt,1);
            int rp = rarg[q];
            if (pos < STALE_CAP) { s_staleq[pos]=q; s_stalec[pos]=rp; }
            atomicExch(&mmask[q], 1ull<<rp);
        }
    }
    __syncthreads();
    const int scnt = (s_scnt < STALE_CAP) ? s_scnt : STALE_CAP;
    for (int j=tid; j<mn; j+=TPB) {
        unsigned long long m = atomicOr(&mmask[s_mlist[j]], 0ull);
        while (m) { int gg = __ffsll(m)-1; m &= m-1ull; atomicAdd(&s_colcnt[gg],1u); }
    }
    __syncthreads();

    // PD: while any column unmatched
    for (int iter=0; iter<1024; ++iter) {
        if (tid < 64) {
            unsigned long long bal = __ballot(s_colcnt[tid]==0u);
            if (tid==0) { s_unm = bal; s_fbmask = 0ull; }
        }
        __syncthreads();
        const unsigned long long unm = s_unm;
        if (unm == 0ull) break;
        mn = s_mn; if (mn > MLIST_CAP) mn = MLIST_CAP;

        for (int j=tid; j<mn; j+=TPB) s_kcnt[s_mlist[j]]++;
        __syncthreads();

        int wq = -1;
        if (tid < 64 && ((unm>>tid)&1ull)) {
            for (int t=0; t<64; ++t) {
                int q = s_pq[tid*64 + t];
                if (s_kcnt[q]==0) { wq=q; break; }
            }
            if (wq < 0) atomicOr(&s_fbmask, 1ull<<tid);
        }
        __syncthreads();
        unsigned long long fb = s_fbmask;
        while (fb) {
            int c = __ffsll(fb)-1; fb &= fb-1ull;
            float bv=__builtin_inff(); int bq=0x7fffffff;
            for (int j=tid; j<Qn; j+=TPB) {
                if (s_kcnt[j]==0) {
                    float v = costb[(size_t)c*Qn + j];
                    if (v<bv || (v==bv && j<bq)) { bv=v; bq=j; }
                }
            }
            s_mv[tid]=bv; s_mi[tid]=bq;
            __syncthreads();
            for (int s=TPB/2; s>0; s>>=1) {
                if (tid<s) {
                    float v2=s_mv[tid+s]; int q2=s_mi[tid+s];
                    if (v2<s_mv[tid] || (v2==s_mv[tid] && q2<s_mi[tid])) { s_mv[tid]=v2; s_mi[tid]=q2; }
                }
                __syncthreads();
            }
            if (tid==0) s_winq[c]=s_mi[0];
            __syncthreads();
        }
        if (tid<64 && wq<0 && ((unm>>tid)&1ull)) wq = s_winq[tid];

        if (tid<64 && ((unm>>tid)&1ull) && wq>=0 && wq<Qn) {
            unsigned long long bit = 1ull<<tid;
            unsigned long long old = atomicOr(&mmask[wq], bit);
            if (old==0ull) {
                int pos = atomicAdd(&s_mn,1);
                if (pos < MLIST_CAP) s_mlist[pos]=wq;
            }
            if (__popcll(old|bit) > 1) s_fix = 1;
            atomicAdd(&s_colcnt[tid],1u);
        }
        __syncthreads();

        if (s_fix) {
            for (int j=tid; j<scnt; j+=TPB) {
                int q = s_staleq[j];
                unsigned int kk = s_kcnt[q];
                float best=__builtin_inff(); int bg=0;
                for (int gg=0; gg<Gn; ++gg) {
                    float v = replay_penalty(costb[(size_t)gg*Qn + q], kk);
                    if (v < best) { best=v; bg=gg; }
                }
                int oc = s_stalec[j];
                if (bg != oc) {
                    atomicAdd(&s_colcnt[oc], (unsigned int)-1);
                    atomicAdd(&s_colcnt[bg], 1u);
                    s_stalec[j] = bg;
                    atomicExch(&mmask[q], 1ull<<bg);
                }
            }
        }
        __syncthreads();
    }

    // PE: outputs (int32)
    __syncthreads();
    mn = s_mn; if (mn > MLIST_CAP) mn = MLIST_CAP;
    unsigned long long* s_mcache = s_pool_raw;
    for (int j=tid; j<mn; j+=TPB) s_mcache[j] = atomicOr(&mmask[s_mlist[j]], 0ull);
    for (int q=tid; q<Qn; q+=TPB) {
        out[(size_t)b*Qn + q] = 0;
        out[(size_t)Bn*Qn + (size_t)b*Qn + q] = 0;
    }
    __syncthreads();
    for (int j=tid; j<mn; j+=TPB) {
        int q = s_mlist[j];
        unsigned long long m = s_mcache[j];
        out[(size_t)b*Qn + q] = 1;
        out[(size_t)Bn*Qn + (size_t)b*Qn + q] = __ffsll(m)-1;
    }
    __syncthreads();
    {
        const int g = tid>>3, p = tid&7;
        float best=__builtin_inff(); int bq=0x7fffffff;
        for (int j=p; j<mn; j+=8) {
            unsigned long long m = s_mcache[j];
            if ((m>>g)&1ull) {
                int q = s_mlist[j];
                float v = replay_penalty(costb[(size_t)g*Qn+q], s_kcnt[q]);
                if (v<best || (v==best && q<bq)) { best=v; bq=q; }
            }
        }
        s_mv[tid]=best; s_mi[tid]=bq;
    }
    __syncthreads();
    if (tid < Gn) {
        float best=__builtin_inff(); int bq=0x7fffffff;
        #pragma unroll
        for (int u=0;u<8;++u) {
            float v=s_mv[tid*8+u]; int qq=s_mi[tid*8+u];
            if (v<best || (v==best && qq<bq)) { best=v; bq=qq; }
        }
        if (bq>=Qn) bq=0;
        out[(size_t)2*Bn*Qn + (size_t)b*Gn + tid] = bq;
    }
}

extern "C" void kernel_launch(void* const* d_in, const int* in_sizes, int n_in,
                              void* d_out, int out_size, void* d_ws, size_t ws_size,
                              hipStream_t stream)
{
    const float* logits = (const float*)d_in[0];
    const float* pboxes = (const float*)d_in[1];
    const int*   labels = (const int*)d_in[2];
    const float* gboxes = (const float*)d_in[3];
    int* out = (int*)d_out;

    char* ws = (char*)d_ws;
    size_t off = 0;
    float* cost_cm = (float*)(ws + off); off += (size_t)Bn*Gn*Qn*sizeof(float);
    float* cls_cm  = (float*)(ws + off); off += (size_t)Bn*Gn*Qn*sizeof(float);
    unsigned long long* mmask = (unsigned long long*)(ws + off); off += (size_t)Bn*Qn*sizeof(unsigned long long);
    float* poolv = (float*)(ws + off); off += (size_t)Bn*Gn*64*sizeof(float);
    int*   poolq = (int*)(ws + off);   off += (size_t)Bn*Gn*64*sizeof(int);
    int*   dynk  = (int*)(ws + off);   off += (size_t)Bn*Gn*sizeof(int);
    unsigned char* rowarg = (unsigned char*)(ws + off); off += (size_t)Bn*Qn;

    dim3 g0((Qn + 63)/64, Bn);
    gather_cls_kernel<<<g0, 256, 0, stream>>>(logits, labels, cls_cm);
    dim3 g1((Qn + 255)/256, Bn);
    build_cost_kernel<<<g1, 256, 0, stream>>>(pboxes, gboxes, cls_cm,
                                              cost_cm, rowarg);
    dim3 g2(Gn, Bn);
    column_select_kernel<<<g2, 512, 0, stream>>>(cost_cm, pboxes, gboxes,
                                                 dynk, poolv, poolq);
    match_kernel<<<Bn, TPB, 0, stream>>>(cost_cm, rowarg, dynk, poolv, poolq, mmask, out);
}